// Round 8
// baseline (41.683 us; speedup 1.0000x reference)
//
#include <hip/hip_runtime.h>
#include <math.h>

// FrequencyAdaptiveNorm: multi-scale (w=5,10,20) centered sliding-window
// normalization over L, softmax-weighted fusion.
// x: (B=32, L=2048, F=256) f32, weights: (3,) f32, out: same shape.
//
// v8 = v7 math + DUAL INDEPENDENT CHAINS per thread. v7's post-mortem:
// VALU work cut 25% but time -4% -> latency/issue-bound, ~4.6 waves/SIMD
// resident each with one serial load chain. Two fully separate
// ring/sum/load chains (adjacent TL=16 chunks) per thread double per-wave
// ILP and loads-in-flight; launch_bounds(256,4) gives the allocator room
// (~2x27 floats live). All state: named scalars + static-index arrays
// (v3 scratch lesson). Edge chunks via the checked scalar path.

#define B_ 32
#define L_ 2048
#define F_ 256
#define TL 16   // rows per chain; 2 chains/thread; grid x = L/(2*TL) = 64

#define RSQ(x) __builtin_amdgcn_rsqf(x)   // single v_rsq_f32, ~1 ulp

__device__ __forceinline__ float fin(float v) {
    return isfinite(v) ? v : 0.0f;   // nan_to_num(nan=0, +inf=0, -inf=0)
}

// ---- one t-step of one chain; all refs resolve to registers after inline --
__device__ __forceinline__ void step(const int t,
                                     float (&r)[21],
                                     float& s5, float& q5, float& s10,
                                     float& q10, float& s20, float& q20,
                                     const float* __restrict__ xb,
                                     float* __restrict__ ob,
                                     const float ws5, const float ws10,
                                     const float ws20) {
    const float eps = 1e-5f;
    const float vnew = fin(xb[(t + 11) * F_]);   // ring insert for next step

    const float xc = r[10];
    float acc;
    {   // w=5
        const float mean = s5 * 0.2f, mean2 = q5 * 0.2f;
        const float var  = fmaxf(fmaf(-mean, mean, mean2), 0.0f);
        acc = ws5 * ((xc - mean) * RSQ(var + eps));
    }
    {   // w=10
        const float mean = s10 * 0.1f, mean2 = q10 * 0.1f;
        const float var  = fmaxf(fmaf(-mean, mean, mean2), 0.0f);
        acc = fmaf(ws10, (xc - mean) * RSQ(var + eps), acc);
    }
    {   // w=20
        const float mean = s20 * 0.05f, mean2 = q20 * 0.05f;
        const float var  = fmaxf(fmaf(-mean, mean, mean2), 0.0f);
        acc = fmaf(ws20, (xc - mean) * RSQ(var + eps), acc);
    }
    ob[t * F_] = acc;

    // slide j -> j+1:  s += a-r;  q += (a-r)(a+r)
    { const float a = r[13], rr = r[8];  const float d = a - rr, p = a + rr; s5  += d; q5  = fmaf(d, p, q5);  }
    { const float a = r[15], rr = r[5];  const float d = a - rr, p = a + rr; s10 += d; q10 = fmaf(d, p, q10); }
    { const float a = r[20], rr = r[0];  const float d = a - rr, p = a + rr; s20 += d; q20 = fmaf(d, p, q20); }

#pragma unroll
    for (int dd = 0; dd < 20; ++dd) r[dd] = r[dd + 1];
    r[20] = vnew;
}

__device__ __forceinline__ void init_chain(const float* __restrict__ xb,
                                           float (&r)[21],
                                           float& s5, float& q5, float& s10,
                                           float& q10, float& s20, float& q20) {
#pragma unroll
    for (int d = 0; d < 21; ++d) r[d] = fin(xb[(d - 10) * F_]);
    s5 = q5 = s10 = q10 = s20 = q20 = 0.f;
#pragma unroll
    for (int d = 0; d < 20; ++d) { s20 += r[d]; q20 = fmaf(r[d], r[d], q20); }
#pragma unroll
    for (int d = 5; d < 15; ++d) { s10 += r[d]; q10 = fmaf(r[d], r[d], q10); }
#pragma unroll
    for (int d = 8; d < 13; ++d) { s5  += r[d]; q5  = fmaf(r[d], r[d], q5);  }
}

// ---- interior fast path: two interleaved independent chains --------------
__device__ __forceinline__ void run_pair(const float* __restrict__ xbA,
                                         float* __restrict__ obA,
                                         const float* __restrict__ xbB,
                                         float* __restrict__ obB,
                                         const float ws5, const float ws10,
                                         const float ws20) {
    float rA[21], rB[21];
    float s5A, q5A, s10A, q10A, s20A, q20A;
    float s5B, q5B, s10B, q10B, s20B, q20B;
    init_chain(xbA, rA, s5A, q5A, s10A, q10A, s20A, q20A);
    init_chain(xbB, rB, s5B, q5B, s10B, q10B, s20B, q20B);

#pragma unroll
    for (int t = 0; t < TL; ++t) {
        step(t, rA, s5A, q5A, s10A, q10A, s20A, q20A, xbA, obA, ws5, ws10, ws20);
        step(t, rB, s5B, q5B, s10B, q10B, s20B, q20B, xbB, obB, ws5, ws10, ws20);
    }
}

// ---- edge: checked scalar path (chunks 0 and 127 only) --------------------
__device__ __forceinline__ void run_edge(const float* __restrict__ xb,
                                         float* __restrict__ ob,
                                         const int l0,
                                         const float ws5, const float ws10,
                                         const float ws20) {
    const float eps = 1e-5f;
    float ring[21];
#pragma unroll
    for (int d = 0; d < 21; ++d) {
        const int l = l0 - 10 + d;
        ring[d] = ((unsigned)l < (unsigned)L_) ? fin(xb[l * F_]) : 0.0f;
    }
    float s5 = 0.f, q5 = 0.f, s10 = 0.f, q10 = 0.f, s20 = 0.f, q20 = 0.f;
#pragma unroll
    for (int d = 0; d < 20; ++d) { s20 += ring[d]; q20 = fmaf(ring[d], ring[d], q20); }
#pragma unroll
    for (int d = 5; d < 15; ++d) { s10 += ring[d]; q10 = fmaf(ring[d], ring[d], q10); }
#pragma unroll
    for (int d = 8; d < 13; ++d) { s5  += ring[d]; q5  = fmaf(ring[d], ring[d], q5);  }

#pragma unroll
    for (int t = 0; t < TL; ++t) {
        const int j = l0 + t;
        const int ln = j + 11;
        const float vnew = ((unsigned)ln < (unsigned)L_) ? fin(xb[ln * F_]) : 0.0f;

        const float xc = ring[10];
        float acc = 0.0f;
        if (j >= 2 && j <= L_ - 3) {
            const float mean = s5 * 0.2f, mean2 = q5 * 0.2f;
            const float var  = fmaxf(fmaf(-mean, mean, mean2), 0.0f);
            acc = fmaf(ws5, (xc - mean) * RSQ(var + eps), acc);
        }
        if (j >= 5 && j <= L_ - 5) {
            const float mean = s10 * 0.1f, mean2 = q10 * 0.1f;
            const float var  = fmaxf(fmaf(-mean, mean, mean2), 0.0f);
            acc = fmaf(ws10, (xc - mean) * RSQ(var + eps), acc);
        }
        if (j >= 10 && j <= L_ - 10) {
            const float mean = s20 * 0.05f, mean2 = q20 * 0.05f;
            const float var  = fmaxf(fmaf(-mean, mean, mean2), 0.0f);
            acc = fmaf(ws20, (xc - mean) * RSQ(var + eps), acc);
        }
        ob[j * F_] = acc;

        { const float a = ring[13], r = ring[8];  const float d = a - r, p = a + r; s5  += d; q5  = fmaf(d, p, q5);  }
        { const float a = ring[15], r = ring[5];  const float d = a - r, p = a + r; s10 += d; q10 = fmaf(d, p, q10); }
        { const float a = ring[20], r = ring[0];  const float d = a - r, p = a + r; s20 += d; q20 = fmaf(d, p, q20); }

#pragma unroll
        for (int d = 0; d < 20; ++d) ring[d] = ring[d + 1];
        ring[20] = vnew;
    }
}

__global__ __launch_bounds__(256, 4)
void fan_kernel(const float* __restrict__ x,
                const float* __restrict__ w,
                float* __restrict__ out) {
    const int f  = threadIdx.x;            // 0..255 == F
    const int b  = blockIdx.y;
    const int l0A = (2 * blockIdx.x)     * TL;   // adjacent chunk pair
    const int l0B = (2 * blockIdx.x + 1) * TL;
    const float* xb = x   + (size_t)b * L_ * F_ + f;
    float*       ob = out + (size_t)b * L_ * F_ + f;

    // softmax over the 3 fusion logits (uniform across threads)
    const float w0 = w[0], w1 = w[1], w2 = w[2];
    const float m  = fmaxf(w0, fmaxf(w1, w2));
    const float e0 = expf(w0 - m), e1 = expf(w1 - m), e2 = expf(w2 - m);
    const float inv = 1.0f / (e0 + e1 + e2);
    const float ws5 = e0 * inv, ws10 = e1 * inv, ws20 = e2 * inv;

    if (blockIdx.x == 0) {
        // chunk 0 is an edge; chunk 1 interior
        run_edge(xb, ob, l0A, ws5, ws10, ws20);
        run_pair(xb + l0B * F_, ob + l0B * F_,            // run chunk 1 alone:
                 xb + l0B * F_, ob + l0B * F_,            // duplicate = harmless
                 ws5, ws10, ws20);
    } else if (blockIdx.x == gridDim.x - 1) {
        // chunk 126 interior; chunk 127 edge
        run_pair(xb + l0A * F_, ob + l0A * F_,
                 xb + l0A * F_, ob + l0A * F_,
                 ws5, ws10, ws20);
        run_edge(xb, ob, l0B, ws5, ws10, ws20);
    } else {
        run_pair(xb + l0A * F_, ob + l0A * F_,
                 xb + l0B * F_, ob + l0B * F_,
                 ws5, ws10, ws20);
    }
}

extern "C" void kernel_launch(void* const* d_in, const int* in_sizes, int n_in,
                              void* d_out, int out_size, void* d_ws, size_t ws_size,
                              hipStream_t stream) {
    const float* x = (const float*)d_in[0];
    const float* w = (const float*)d_in[1];
    float* out = (float*)d_out;
    (void)in_sizes; (void)n_in; (void)out_size; (void)d_ws; (void)ws_size;

    dim3 grid(L_ / (2 * TL), B_);   // (64, 32) = 2048 blocks
    dim3 block(F_);                 // 256 threads, one per feature column
    hipLaunchKernelGGL(fan_kernel, grid, block, 0, stream, x, w, out);
}

// Round 9
// 32.465 us; speedup vs baseline: 1.2839x; 1.2839x over previous
//
#include <hip/hip_runtime.h>
#include <math.h>

// FrequencyAdaptiveNorm: multi-scale (w=5,10,20) centered sliding-window
// normalization over L, softmax-weighted fusion.
// x: (B=32, L=2048, F=256) f32, weights: (3,) f32, out: same shape.
//
// v9 = v7 (best, 33.5us) with ONE change: ring extended 21 -> 24 entries.
// v7's per-iteration load x[j+11] was consumed 1 iteration later (a20)
// -> ~100 issue-cycles of distance vs 200-400cy L2/L3 latency -> stall.
// With ring[24] the load is x[j+14], consumed 4 iterations later (~280+
// issue-cycles): latency hidden inside one wave. +3 VGPR, indices static,
// shift remains SSA renaming. (v5/v6/v8 lesson: structural ILP rewrites
// fail; only dataflow-distance changes inside the proven structure work.)

#define B_ 32
#define L_ 2048
#define F_ 256
#define TL 32     // L-chunk per block; grid = (64, 32) = 2048 blocks
#define NR 24     // ring size; ring[d] = x[j-10+d]; insert at d=23 (j+14)

#define RSQ(x) __builtin_amdgcn_rsqf(x)   // single v_rsq_f32, ~1 ulp

__device__ __forceinline__ float fin(float v) {
    return isfinite(v) ? v : 0.0f;   // nan_to_num(nan=0, +inf=0, -inf=0)
}

template <bool CHECKED>
__device__ __forceinline__ void run_chunk(const float* __restrict__ xb,
                                          float* __restrict__ ob,
                                          const int l0,
                                          const float ws5, const float ws10,
                                          const float ws20) {
    const float eps = 1e-5f;

    // delay line: ring[d] = x[l0-10+d], d = 0..NR-1
    float ring[NR];
#pragma unroll
    for (int d = 0; d < NR; ++d) {
        const int l = l0 - 10 + d;
        float v;
        if (CHECKED)
            v = ((unsigned)l < (unsigned)L_) ? xb[l * F_] : 0.0f;
        else
            v = xb[l * F_];
        ring[d] = fin(v);
    }

    // running sums at j=l0: w5=ring[8..12], w10=ring[5..14], w20=ring[0..19]
    float s5 = 0.f, q5 = 0.f, s10 = 0.f, q10 = 0.f, s20 = 0.f, q20 = 0.f;
#pragma unroll
    for (int d = 0; d < 20; ++d) { s20 += ring[d]; q20 = fmaf(ring[d], ring[d], q20); }
#pragma unroll
    for (int d = 5; d < 15; ++d) { s10 += ring[d]; q10 = fmaf(ring[d], ring[d], q10); }
#pragma unroll
    for (int d = 8; d < 13; ++d) { s5  += ring[d]; q5  = fmaf(ring[d], ring[d], q5);  }

#pragma unroll
    for (int t = 0; t < TL; ++t) {
        const int j = l0 + t;

        // ring-insert load, 4 iterations ahead of first use
        float vnew;
        if (CHECKED) {
            const int ln = j + 14;
            vnew = ((unsigned)ln < (unsigned)L_) ? fin(xb[ln * F_]) : 0.0f;
        } else {
            vnew = fin(xb[(j + 14) * F_]);
        }

        const float xc = ring[10];
        float acc = 0.0f;

        if (!CHECKED || (j >= 2 && j <= L_ - 3)) {          // w=5
            const float mean  = s5 * 0.2f;
            const float mean2 = q5 * 0.2f;
            const float var   = fmaxf(fmaf(-mean, mean, mean2), 0.0f);
            acc = fmaf(ws5, (xc - mean) * RSQ(var + eps), acc);
        }
        if (!CHECKED || (j >= 5 && j <= L_ - 5)) {          // w=10
            const float mean  = s10 * 0.1f;
            const float mean2 = q10 * 0.1f;
            const float var   = fmaxf(fmaf(-mean, mean, mean2), 0.0f);
            acc = fmaf(ws10, (xc - mean) * RSQ(var + eps), acc);
        }
        if (!CHECKED || (j >= 10 && j <= L_ - 10)) {        // w=20
            const float mean  = s20 * 0.05f;
            const float mean2 = q20 * 0.05f;
            const float var   = fmaxf(fmaf(-mean, mean, mean2), 0.0f);
            acc = fmaf(ws20, (xc - mean) * RSQ(var + eps), acc);
        }
        ob[j * F_] = acc;

        // slide windows j -> j+1:  s += a-r;  q += (a-r)(a+r)
        {
            const float a = ring[13], r = ring[8];
            const float d = a - r, p = a + r;
            s5 += d; q5 = fmaf(d, p, q5);
        }
        {
            const float a = ring[15], r = ring[5];
            const float d = a - r, p = a + r;
            s10 += d; q10 = fmaf(d, p, q10);
        }
        {
            const float a = ring[20], r = ring[0];
            const float d = a - r, p = a + r;
            s20 += d; q20 = fmaf(d, p, q20);
        }

        // shift delay line — full unroll makes this pure register renaming
#pragma unroll
        for (int d = 0; d < NR - 1; ++d) ring[d] = ring[d + 1];
        ring[NR - 1] = vnew;
    }
}

__global__ __launch_bounds__(256, 8)
void fan_kernel(const float* __restrict__ x,
                const float* __restrict__ w,
                float* __restrict__ out) {
    const int f  = threadIdx.x;           // 0..255 == F
    const int b  = blockIdx.y;
    const int l0 = blockIdx.x * TL;
    const float* xb = x   + (size_t)b * L_ * F_ + f;
    float*       ob = out + (size_t)b * L_ * F_ + f;

    // softmax over the 3 fusion logits (uniform across threads)
    const float w0 = w[0], w1 = w[1], w2 = w[2];
    const float m  = fmaxf(w0, fmaxf(w1, w2));
    const float e0 = expf(w0 - m), e1 = expf(w1 - m), e2 = expf(w2 - m);
    const float inv = 1.0f / (e0 + e1 + e2);
    const float ws5 = e0 * inv, ws10 = e1 * inv, ws20 = e2 * inv;

    // interior blocks 1..62: loads span [l0-10, l0+TL+13] -> in range, and
    // all three window validity ranges cover every j in the chunk.
    if (blockIdx.x != 0 && blockIdx.x != gridDim.x - 1)
        run_chunk<false>(xb, ob, l0, ws5, ws10, ws20);
    else
        run_chunk<true>(xb, ob, l0, ws5, ws10, ws20);
}

extern "C" void kernel_launch(void* const* d_in, const int* in_sizes, int n_in,
                              void* d_out, int out_size, void* d_ws, size_t ws_size,
                              hipStream_t stream) {
    const float* x = (const float*)d_in[0];
    const float* w = (const float*)d_in[1];
    float* out = (float*)d_out;
    (void)in_sizes; (void)n_in; (void)out_size; (void)d_ws; (void)ws_size;

    dim3 grid(L_ / TL, B_);   // (64, 32) = 2048 blocks
    dim3 block(F_);           // 256 threads, one per feature column
    hipLaunchKernelGGL(fan_kernel, grid, block, 0, stream, x, w, out);
}